// Round 10
// baseline (470.920 us; speedup 1.0000x reference)
//
#include <hip/hip_runtime.h>
#include <math.h>

#define NEG_SLOPE 0.01f
#define ELLW 40   // max in-degree per relation (Poisson(10); P(overflow)~1e-8, clamped)

typedef float f4 __attribute__((ext_vector_type(4)));
typedef __bf16 bf16x8 __attribute__((ext_vector_type(8)));
typedef __bf16 bf16x4 __attribute__((ext_vector_type(4)));

// ---------------- W prep (transpose + bf16 split, 5 weights) + zero degree region ----------------
__global__ __launch_bounds__(256) void prep_w_zero(
    const float* __restrict__ W0, const float* __restrict__ W1,
    const float* __restrict__ W2, const float* __restrict__ W3,
    const float* __restrict__ W4, __bf16* __restrict__ H, __bf16* __restrict__ L,
    int* __restrict__ zp, int zN)
{
    const int b = blockIdx.x;
    if (b < 320) {
        const int y = b >> 6;
        const float* W = y == 0 ? W0 : y == 1 ? W1 : y == 2 ? W2 : y == 3 ? W3 : W4;
        int idx = (b & 63) * 256 + threadIdx.x;   // 0..16383
        int k = idx >> 7, n = idx & 127;
        float w = W[idx];
        __bf16 h = (__bf16)w;
        __bf16 l = (__bf16)(w - (float)h);
        H[(size_t)y * 16384 + n * 128 + k] = h;
        L[(size_t)y * 16384 + n * 128 + k] = l;
    } else {
        int i = (b - 320) * 256 + threadIdx.x;
        if (i < zN) zp[i] = 0;
    }
}

// ---------------- MFMA GEMM core (bf16 3-split, unscaled): C[BM,128] = f(A) @ W ----------------
// MI=2 -> BM=64 (34.8 KB LDS); MI=1 -> BM=32 (17.4 KB LDS)
template <int RELU, int MI>
__device__ __forceinline__ void gemm_core(const float* __restrict__ A,
    const __bf16* __restrict__ Bh, const __bf16* __restrict__ Bl,
    float* __restrict__ C, int M, int row0, int tid,
    __bf16 (*Ah)[136], __bf16 (*Al)[136])
{
#pragma unroll
    for (int it = 0; it < MI * 4; ++it) {
        int idx4 = it * 256 + tid;
        int r = idx4 >> 5;
        int c = (idx4 & 31) << 2;
        int rg = row0 + r;
        f4 v = {0.f, 0.f, 0.f, 0.f};
        if (rg < M) v = *(const f4*)(A + (size_t)rg * 128 + c);
        if (RELU) {
#pragma unroll
            for (int j = 0; j < 4; ++j) v[j] = v[j] >= 0.f ? v[j] : v[j] * NEG_SLOPE;
        }
        bf16x4 hv, lv;
#pragma unroll
        for (int j = 0; j < 4; ++j) {
            __bf16 h = (__bf16)v[j];
            hv[j] = h;
            lv[j] = (__bf16)(v[j] - (float)h);
        }
        *(bf16x4*)&Ah[r][c] = hv;
        *(bf16x4*)&Al[r][c] = lv;
    }
    __syncthreads();

    const int lane = tid & 63;
    const int wid = tid >> 6;
    const int lm = lane & 15;
    const int lq = lane >> 4;
    const int mbase = (wid & 1) * (MI * 16);
    const int nbase = (wid >> 1) * 64;

    f4 acc[MI][4] = {};
#pragma unroll
    for (int kc = 0; kc < 4; ++kc) {
        const int koff = kc * 32 + lq * 8;
        bf16x8 ah[MI], al[MI], bh[4], bl[4];
#pragma unroll
        for (int mi = 0; mi < MI; ++mi) {
            ah[mi] = *(const bf16x8*)&Ah[mbase + mi * 16 + lm][koff];
            al[mi] = *(const bf16x8*)&Al[mbase + mi * 16 + lm][koff];
        }
#pragma unroll
        for (int ni = 0; ni < 4; ++ni) {
            size_t boff = (size_t)(nbase + ni * 16 + lm) * 128 + koff;
            bh[ni] = *(const bf16x8*)(Bh + boff);
            bl[ni] = *(const bf16x8*)(Bl + boff);
        }
#pragma unroll
        for (int mi = 0; mi < MI; ++mi)
#pragma unroll
            for (int ni = 0; ni < 4; ++ni) {
                acc[mi][ni] = __builtin_amdgcn_mfma_f32_16x16x32_bf16(ah[mi], bh[ni], acc[mi][ni], 0, 0, 0);
                acc[mi][ni] = __builtin_amdgcn_mfma_f32_16x16x32_bf16(al[mi], bh[ni], acc[mi][ni], 0, 0, 0);
                acc[mi][ni] = __builtin_amdgcn_mfma_f32_16x16x32_bf16(ah[mi], bl[ni], acc[mi][ni], 0, 0, 0);
            }
    }

#pragma unroll
    for (int mi = 0; mi < MI; ++mi) {
        int rbase = row0 + mbase + mi * 16 + lq * 4;
#pragma unroll
        for (int r = 0; r < 4; ++r) {
            int row = rbase + r;
            if (row < M) {
#pragma unroll
                for (int ni = 0; ni < 4; ++ni)
                    C[(size_t)row * 128 + nbase + ni * 16 + lm] = acc[mi][ni][r];
            }
        }
    }
}

// ---------------- build helper: one 256-edge block of degree+ELL ----------------
__device__ __forceinline__ void build_edges(const int* __restrict__ src,
    const int* __restrict__ dst, int* __restrict__ sdeg, int* __restrict__ cnt,
    int* __restrict__ ell, int E, int base, int tid)
{
    int i = base * 256 + tid;
    if (i < E) {
        int s = src[i];
        int d = dst[i];
        atomicAdd(&sdeg[s], 1);
        int p = atomicAdd(&cnt[d], 1);
        if (p < ELLW) ell[d * ELLW + p] = s;
    }
}

// ---------------- gather helpers: half-wave paired-edge accumulate (f4/lane) ----------------
__device__ __forceinline__ void rel_accum4(const float* __restrict__ feat,
    const int* __restrict__ cp, int n, const int* __restrict__ sdeg,
    int half, int c4, f4& acc)
{
    int i = half;
    for (; i + 2 < n; i += 4) {
        int q0 = cp[i], q1 = cp[i + 2];
        float w0 = rsqrtf(fmaxf((float)sdeg[q0], 1.0f));
        float w1 = rsqrtf(fmaxf((float)sdeg[q1], 1.0f));
        f4 v0 = *(const f4*)(feat + (size_t)q0 * 128 + c4);
        f4 v1 = *(const f4*)(feat + (size_t)q1 * 128 + c4);
        acc += v0 * w0;
        acc += v1 * w1;
    }
    if (i < n) {
        int q0 = cp[i];
        float w0 = rsqrtf(fmaxf((float)sdeg[q0], 1.0f));
        f4 v0 = *(const f4*)(feat + (size_t)q0 * 128 + c4);
        acc += v0 * w0;
    }
}

__device__ __forceinline__ f4 xhalf_sum(f4 r)
{
    f4 o;
    o[0] = __shfl_xor(r[0], 32);
    o[1] = __shfl_xor(r[1], 32);
    o[2] = __shfl_xor(r[2], 32);
    o[3] = __shfl_xor(r[3], 32);
    return r + o;
}

// dual-relation row gather -> out (adds both biases)
__device__ __forceinline__ void dual_gather_row(
    const float* __restrict__ fA, const int* __restrict__ ellA,
    const int* __restrict__ cntA, const int* __restrict__ degsA,
    const float* __restrict__ fB, const int* __restrict__ ellB,
    const int* __restrict__ cntB, const int* __restrict__ degsB,
    const float* __restrict__ bA, const float* __restrict__ bB,
    float* __restrict__ out, int row, int tid)
{
    const int lane = tid & 63;
    const int half = lane >> 5;
    const int c4 = (lane & 31) << 2;
    int na = cntA[row];
    float wa = rsqrtf(fmaxf((float)na, 1.0f));
    if (na > ELLW) na = ELLW;
    f4 accA = {0.f, 0.f, 0.f, 0.f};
    rel_accum4(fA, ellA + row * ELLW, na, degsA, half, c4, accA);
    int nb = cntB[row];
    float wb = rsqrtf(fmaxf((float)nb, 1.0f));
    if (nb > ELLW) nb = ELLW;
    f4 accB = {0.f, 0.f, 0.f, 0.f};
    rel_accum4(fB, ellB + row * ELLW, nb, degsB, half, c4, accB);
    f4 r = accA * wa + accB * wb;
    r = xhalf_sum(r);
    if (half == 0) {
        r += *(const f4*)(bA + c4);
        r += *(const f4*)(bB + c4);
        *(f4*)(out + (size_t)row * 128 + c4) = r;
    }
}

// ---------------- A: build_cg + all three layer-1 GEMMs (1:1 interleave) ----------------
__global__ __launch_bounds__(256) void fused_A(
    const int* __restrict__ s1, const int* __restrict__ d1,
    int* sd1, int* c1, int* e1, int E1, int B1,
    const float* __restrict__ xc, const float* __restrict__ xg,
    const __bf16* __restrict__ wt_h, const __bf16* __restrict__ wt_l,
    float* __restrict__ t_cg, float* __restrict__ t_cc, float* __restrict__ t_gc,
    int Nc, int Ng, int gBc, int G)
{
    __shared__ __bf16 Ah[64][136];
    __shared__ __bf16 Al[64][136];
    const int r2 = blockIdx.x & 1, q = blockIdx.x >> 1;
    if (r2 == 0) {
        if (q >= G) return;
        if (q < gBc)
            gemm_core<0, 2>(xc, wt_h, wt_l, t_cg, Nc, q * 64, threadIdx.x, Ah, Al);
        else if (q < 2 * gBc)
            gemm_core<0, 2>(xc, wt_h + 16384, wt_l + 16384, t_cc, Nc, (q - gBc) * 64, threadIdx.x, Ah, Al);
        else
            gemm_core<0, 2>(xg, wt_h + 2 * 16384, wt_l + 2 * 16384, t_gc, Ng, (q - 2 * gBc) * 64, threadIdx.x, Ah, Al);
    } else {
        if (q >= B1) return;
        build_edges(s1, d1, sd1, c1, e1, E1, q, threadIdx.x);
    }
}

// ---------------- B: build_cc + build_gc + gather_gene (1 build : 2 gather) ----------------
__global__ __launch_bounds__(256) void fused_B(
    const int* __restrict__ s0, const int* __restrict__ d0, int* sd0, int* c0, int* e0, int E0, int B0,
    const int* __restrict__ s2, const int* __restrict__ d2, int* sd2, int* c2, int* e2, int E2, int B2,
    const float* __restrict__ t_cg, const int* __restrict__ ell_cg,
    const int* __restrict__ cnt_cg, const int* __restrict__ degs_cg,
    const float* __restrict__ b1_cg, float* __restrict__ h1_gene, int Ng, int Bg)
{
    const int r3 = blockIdx.x % 3, q = blockIdx.x / 3;
    if (r3 == 0) {
        if (q < B0) build_edges(s0, d0, sd0, c0, e0, E0, q, threadIdx.x);
        else if (q < B0 + B2) build_edges(s2, d2, sd2, c2, e2, E2, q - B0, threadIdx.x);
    } else {
        int g = q * 2 + (r3 - 1);
        if (g >= Bg) return;
        int row = g * 4 + ((int)threadIdx.x >> 6);
        if (row >= Ng) return;
        const int lane = threadIdx.x & 63;
        const int half = lane >> 5;
        const int c4 = (lane & 31) << 2;
        int n = cnt_cg[row];
        float wd = rsqrtf(fmaxf((float)n, 1.0f));
        if (n > ELLW) n = ELLW;
        f4 acc = {0.f, 0.f, 0.f, 0.f};
        rel_accum4(t_cg, ell_cg + row * ELLW, n, degs_cg, half, c4, acc);
        f4 r = acc * wd;
        r = xhalf_sum(r);
        if (half == 0) {
            r += *(const f4*)(b1_cg + c4);
            *(f4*)(h1_gene + (size_t)row * 128 + c4) = r;
        }
    }
}

// ---------------- C: gather_chem (cc+gc -> h1_chem) + gemm2_gc (BM=32) ----------------
__global__ __launch_bounds__(256) void fused_C(
    const float* __restrict__ f_cc, const int* __restrict__ ell_cc,
    const int* __restrict__ cnt_cc, const int* __restrict__ degs_cc,
    const float* __restrict__ t_gc, const int* __restrict__ ell_gc,
    const int* __restrict__ cnt_gc, const int* __restrict__ degs_gc,
    const float* __restrict__ b1_cc, const float* __restrict__ b1_gc,
    float* __restrict__ h1_chem, int Nc, int Bc,
    const float* __restrict__ h1_gene, const __bf16* __restrict__ wt_h,
    const __bf16* __restrict__ wt_l, float* __restrict__ t2_gc, int Ng, int gBg32)
{
    __shared__ __bf16 Ah[32][136];
    __shared__ __bf16 Al[32][136];
    const int r14 = blockIdx.x % 14, q = blockIdx.x / 14;
    if (r14 == 0) {
        if (q >= gBg32) return;
        gemm_core<1, 1>(h1_gene, wt_h + 4 * 16384, wt_l + 4 * 16384, t2_gc, Ng, q * 32, threadIdx.x, Ah, Al);
    } else {
        int g = q * 13 + (r14 - 1);
        if (g >= Bc) return;
        int row = g * 4 + ((int)threadIdx.x >> 6);
        if (row >= Nc) return;
        dual_gather_row(f_cc, ell_cc, cnt_cc, degs_cc,
                        t_gc, ell_gc, cnt_gc, degs_gc,
                        b1_cc, b1_gc, h1_chem, row, threadIdx.x);
    }
}

// ---------------- D: gemm2_cc (BM=64) ----------------
__global__ __launch_bounds__(256) void gemm2_cc(const float* __restrict__ h1c,
    const __bf16* __restrict__ wt_h, const __bf16* __restrict__ wt_l,
    float* __restrict__ t2_cc, int Nc)
{
    __shared__ __bf16 Ah[64][136];
    __shared__ __bf16 Al[64][136];
    gemm_core<1, 2>(h1c, wt_h + 3 * 16384, wt_l + 3 * 16384, t2_cc, Nc, blockIdx.x * 64, threadIdx.x, Ah, Al);
}

// ---------------- E: final dual gather -> d_out ----------------
__global__ __launch_bounds__(256) void gather_l2(
    const float* __restrict__ fA, const int* __restrict__ ellA,
    const int* __restrict__ cntA, const int* __restrict__ degsA,
    const float* __restrict__ fB, const int* __restrict__ ellB,
    const int* __restrict__ cntB, const int* __restrict__ degsB,
    const float* __restrict__ bA, const float* __restrict__ bB,
    float* __restrict__ out, int Nd)
{
    int row = blockIdx.x * 4 + ((int)threadIdx.x >> 6);
    if (row >= Nd) return;
    dual_gather_row(fA, ellA, cntA, degsA, fB, ellB, cntB, degsB,
                    bA, bB, out, row, threadIdx.x);
}

extern "C" void kernel_launch(void* const* d_in, const int* in_sizes, int n_in,
                              void* d_out, int out_size, void* d_ws, size_t ws_size,
                              hipStream_t stream)
{
    const float* x_chem = (const float*)d_in[0];
    const float* x_gene = (const float*)d_in[1];
    const int* src_cc = (const int*)d_in[2];
    const int* dst_cc = (const int*)d_in[3];
    const int* src_cg = (const int*)d_in[4];
    const int* dst_cg = (const int*)d_in[5];
    const int* src_gc = (const int*)d_in[6];
    const int* dst_gc = (const int*)d_in[7];
    const float* W1_cc = (const float*)d_in[8];
    const float* W1_cg = (const float*)d_in[9];
    const float* W1_gc = (const float*)d_in[10];
    const float* W2_cc = (const float*)d_in[11];
    const float* W2_gc = (const float*)d_in[13];
    const float* b1_cc = (const float*)d_in[14];
    const float* b1_cg = (const float*)d_in[15];
    const float* b1_gc = (const float*)d_in[16];
    const float* b2_cc = (const float*)d_in[17];
    const float* b2_gc = (const float*)d_in[19];
    (void)n_in; (void)out_size; (void)ws_size;

    const int Nc = in_sizes[0] / 128;
    const int Ng = in_sizes[1] / 128;
    const int Ecc = in_sizes[2];
    const int Ecg = in_sizes[4];
    const int Egc = in_sizes[6];

    // ---------------- workspace layout ----------------
    int* ip = (int*)d_ws;
    int* cnt_cc  = ip; ip += Nc;   // zeroed region start
    int* cnt_cg  = ip; ip += Ng;
    int* cnt_gc  = ip; ip += Nc;
    int* degs_cc = ip; ip += Nc;
    int* degs_cg = ip; ip += Nc;
    int* degs_gc = ip; ip += Ng;
    const int degTotal = 4 * Nc + 2 * Ng;
    int* ell_cc = ip; ip += (size_t)Nc * ELLW;
    int* ell_cg = ip; ip += (size_t)Ng * ELLW;
    int* ell_gc = ip; ip += (size_t)Nc * ELLW;
    size_t intCount = (size_t)(ip - (int*)d_ws);
    intCount = (intCount + 3) & ~(size_t)3;
    float* fp = (float*)d_ws + intCount;
    float* h1_chem = fp; fp += (size_t)Nc * 128;
    float* h1_gene = fp; fp += (size_t)Ng * 128;
    float* t_cg    = fp; fp += (size_t)Nc * 128;   // layer1 cg feat; reused as t2_cc after C
    float* t_gc    = fp; fp += (size_t)Ng * 128;   // layer1 gc feat
    float* t2_gc   = fp; fp += (size_t)Ng * 128;   // layer2 gc feat (separate: race-free in C)
    __bf16* wt_h = (__bf16*)fp;                    // 5 * 16384 bf16
    __bf16* wt_l = wt_h + 5 * 16384;
    float* outF = (float*)d_out;                   // doubles as layer1 cc feat
    float* t2_cc = t_cg;                           // dead after C -> reuse

    dim3 blk(256);
    const int B0 = (Ecc + 255) / 256, B1 = (Ecg + 255) / 256, B2 = (Egc + 255) / 256;
    const int gBc = (Nc + 63) / 64, gBg = (Ng + 63) / 64;
    const int G = 2 * gBc + gBg;
    const int gBg32 = (Ng + 31) / 32;
    const int Bg = (Ng + 3) / 4, Bc = (Nc + 3) / 4;

    // prep: W transpose/split + zero degree region
    const int zB = (degTotal + 255) / 256;
    prep_w_zero<<<320 + zB, blk, 0, stream>>>(W1_cg, W1_cc, W1_gc, W2_cc, W2_gc,
        wt_h, wt_l, (int*)d_ws, degTotal);

    // A: build_cg + all layer-1 GEMMs
    {
        int Q = G > B1 ? G : B1;
        fused_A<<<2 * Q, blk, 0, stream>>>(
            src_cg, dst_cg, degs_cg, cnt_cg, ell_cg, Ecg, B1,
            x_chem, x_gene, wt_h, wt_l, t_cg, outF, t_gc, Nc, Ng, gBc, G);
    }

    // B: build_cc + build_gc + gather_gene (cg -> h1_gene)
    {
        int EBb = B0 + B2;
        int Q = EBb > (Bg + 1) / 2 ? EBb : (Bg + 1) / 2;
        fused_B<<<3 * Q, blk, 0, stream>>>(
            src_cc, dst_cc, degs_cc, cnt_cc, ell_cc, Ecc, B0,
            src_gc, dst_gc, degs_gc, cnt_gc, ell_gc, Egc, B2,
            t_cg, ell_cg, cnt_cg, degs_cg, b1_cg, h1_gene, Ng, Bg);
    }

    // C: gather_chem (cc+gc -> h1_chem) + gemm2_gc (h1_gene -> t2_gc)
    {
        int Q = gBg32 > (Bc + 12) / 13 ? gBg32 : (Bc + 12) / 13;
        fused_C<<<14 * Q, blk, 0, stream>>>(
            outF, ell_cc, cnt_cc, degs_cc,
            t_gc, ell_gc, cnt_gc, degs_gc,
            b1_cc, b1_gc, h1_chem, Nc, Bc,
            h1_gene, wt_h, wt_l, t2_gc, Ng, gBg32);
    }

    // D: gemm2_cc (h1_chem -> t2_cc)
    gemm2_cc<<<gBc, blk, 0, stream>>>(h1_chem, wt_h, wt_l, t2_cc, Nc);

    // E: final dual gather -> out
    gather_l2<<<Bc, blk, 0, stream>>>(
        t2_cc, ell_cc, cnt_cc, degs_cc,
        t2_gc, ell_gc, cnt_gc, degs_gc,
        b2_cc, b2_gc, outF, Nc);
}